// Round 1
// baseline (138.153 us; speedup 1.0000x reference)
//
#include <hip/hip_runtime.h>
#include <math.h>

#define NP 16384   // spatial positions = 32*32*16
#define KD 128     // inner (channel) dimension of both GEMMs
#define HDIM 32
#define WDIM 32
#define ZDIM 16

// ---------------------------------------------------------------------------
// Tiled f32 GEMM: C[o][p] = sum_c A[o][c] * B[c][p] + bias[o]
// A: M x 128 row-major, B: 128 x NP, C: M x NP.  Grid: (NP/64, M/64), 256 thr.
// ---------------------------------------------------------------------------
__global__ __launch_bounds__(256) void gemm_f32(
    const float* __restrict__ A, const float* __restrict__ B,
    const float* __restrict__ bias, float* __restrict__ C)
{
    __shared__ __align__(16) float Ws[KD][68];  // [c][o_local], padded
    __shared__ __align__(16) float Xs[KD][64];  // [c][p_local]

    const int o0 = blockIdx.y * 64;
    const int p0 = blockIdx.x * 64;
    const int tid = threadIdx.x;

    // Load A tile transposed into LDS: Ws[c][i] = A[(o0+i)*KD + c]
    #pragma unroll
    for (int e = tid; e < 64 * KD; e += 256) {
        const int i = e >> 7;        // o_local 0..63
        const int c = e & (KD - 1);  // 0..127
        Ws[c][i] = A[(o0 + i) * KD + c];
    }
    // Load B tile: Xs[c][j] = B[c*NP + p0 + j]
    #pragma unroll
    for (int e = tid; e < KD * 64; e += 256) {
        const int c = e >> 6;
        const int j = e & 63;
        Xs[c][j] = B[c * NP + p0 + j];
    }
    __syncthreads();

    const int tx = tid & 15;   // p group
    const int ty = tid >> 4;   // o group
    float acc[4][4] = {{0.f, 0.f, 0.f, 0.f},
                       {0.f, 0.f, 0.f, 0.f},
                       {0.f, 0.f, 0.f, 0.f},
                       {0.f, 0.f, 0.f, 0.f}};

    #pragma unroll 4
    for (int kk = 0; kk < KD; ++kk) {
        const float4 wf = *(const float4*)&Ws[kk][ty * 4];
        const float4 xf = *(const float4*)&Xs[kk][tx * 4];
        const float wv[4] = {wf.x, wf.y, wf.z, wf.w};
        const float xv[4] = {xf.x, xf.y, xf.z, xf.w};
        #pragma unroll
        for (int i = 0; i < 4; ++i)
            #pragma unroll
            for (int j = 0; j < 4; ++j)
                acc[i][j] = fmaf(wv[i], xv[j], acc[i][j]);
    }

    #pragma unroll
    for (int i = 0; i < 4; ++i) {
        const int o = o0 + ty * 4 + i;
        const float bo = bias[o];
        float4 r;
        r.x = acc[i][0] + bo;
        r.y = acc[i][1] + bo;
        r.z = acc[i][2] + bo;
        r.w = acc[i][3] + bo;
        *(float4*)&C[o * NP + p0 + tx * 4] = r;
    }
}

// ---------------------------------------------------------------------------
// 3D neighborhood attention, k=3x3x3 (27 neighbors), NATTEN clamped windows.
// qkv layout: [384][NP]; q rows 0..127, k rows 128..255, v rows 256..383.
// Head n owns channels n*32..n*32+31.  One thread per (head, position).
// Grid: (NP/256, heads), 256 threads.
// ---------------------------------------------------------------------------
__global__ __launch_bounds__(256) void natten3d(
    const float* __restrict__ qkv, const float* __restrict__ rpb,
    float* __restrict__ attnout)
{
    const int tid  = threadIdx.x;
    const int head = blockIdx.y;
    const int p    = blockIdx.x * 256 + tid;
    const int h = p >> 9;
    const int w = (p >> 4) & 31;
    const int z = p & 15;

    __shared__ float bias_s[125];
    if (tid < 125) bias_s[tid] = rpb[head * 125 + tid];
    __syncthreads();

    const float scale = 0.17677669529663687f;  // 32^-0.5

    const float* __restrict__ qb = qkv + (head * 32) * NP;
    const float* __restrict__ kb = qkv + (128 + head * 32) * NP;
    const float* __restrict__ vb = qkv + (256 + head * 32) * NP;

    float q[32];
    #pragma unroll
    for (int d = 0; d < 32; ++d) q[d] = qb[d * NP + p] * scale;

    int hs = h - 1; hs = hs < 0 ? 0 : (hs > HDIM - 3 ? HDIM - 3 : hs);
    int ws_ = w - 1; ws_ = ws_ < 0 ? 0 : (ws_ > WDIM - 3 ? WDIM - 3 : ws_);
    int zs = z - 1; zs = zs < 0 ? 0 : (zs > ZDIM - 3 ? ZDIM - 3 : zs);
    const int rh0 = hs - h + 2;   // relative-bias base index per dim (0..2)
    const int rw0 = ws_ - w + 2;
    const int rz0 = zs - z + 2;

    float s[27];
    float smax = -1e30f;
    #pragma unroll
    for (int dh = 0; dh < 3; ++dh) {
        #pragma unroll
        for (int dw = 0; dw < 3; ++dw) {
            #pragma unroll
            for (int dz = 0; dz < 3; ++dz) {
                const int m = (dh * 3 + dw) * 3 + dz;
                const int pn = (hs + dh) * 512 + (ws_ + dw) * 16 + (zs + dz);
                float acc = bias_s[((rh0 + dh) * 5 + (rw0 + dw)) * 5 + (rz0 + dz)];
                #pragma unroll
                for (int d = 0; d < 32; ++d)
                    acc = fmaf(q[d], kb[d * NP + pn], acc);
                s[m] = acc;
                smax = fmaxf(smax, acc);
            }
        }
    }

    float ssum = 0.f;
    #pragma unroll
    for (int m = 0; m < 27; ++m) {
        s[m] = __expf(s[m] - smax);
        ssum += s[m];
    }
    const float inv = 1.f / ssum;

    float o[32];
    #pragma unroll
    for (int d = 0; d < 32; ++d) o[d] = 0.f;

    #pragma unroll
    for (int dh = 0; dh < 3; ++dh) {
        #pragma unroll
        for (int dw = 0; dw < 3; ++dw) {
            #pragma unroll
            for (int dz = 0; dz < 3; ++dz) {
                const int m = (dh * 3 + dw) * 3 + dz;
                const int pn = (hs + dh) * 512 + (ws_ + dw) * 16 + (zs + dz);
                const float pm = s[m];
                #pragma unroll
                for (int d = 0; d < 32; ++d)
                    o[d] = fmaf(pm, vb[d * NP + pn], o[d]);
            }
        }
    }

    #pragma unroll
    for (int d = 0; d < 32; ++d)
        attnout[(head * 32 + d) * NP + p] = o[d] * inv;
}

// ---------------------------------------------------------------------------
extern "C" void kernel_launch(void* const* d_in, const int* in_sizes, int n_in,
                              void* d_out, int out_size, void* d_ws, size_t ws_size,
                              hipStream_t stream)
{
    const float* x    = (const float*)d_in[0];  // (1,128,32,32,16)
    const float* Wqkv = (const float*)d_in[1];  // (384,128)
    const float* bqkv = (const float*)d_in[2];  // (384,)
    const float* rpb  = (const float*)d_in[3];  // (4,5,5,5)
    const float* Wp   = (const float*)d_in[4];  // (128,128)
    const float* bp   = (const float*)d_in[5];  // (128,)
    float* out = (float*)d_out;                 // (1,128,32,32,16)

    float* qkv     = (float*)d_ws;              // 384*NP f32 = 24 MB
    float* attnout = qkv + 384 * NP;            // 128*NP f32 =  8 MB

    // 1) QKV projection: qkv[o][p] = Wqkv[o][:] . x[:][p] + bqkv[o]
    gemm_f32<<<dim3(NP / 64, 6), dim3(256), 0, stream>>>(Wqkv, x, bqkv, qkv);

    // 2) neighborhood attention per head
    natten3d<<<dim3(NP / 256, 4), dim3(256), 0, stream>>>(qkv, rpb, attnout);

    // 3) output projection: out[o][p] = Wp[o][:] . attnout[:][p] + bp[o]
    gemm_f32<<<dim3(NP / 64, 2), dim3(256), 0, stream>>>(Wp, attnout, bp, out);
}

// Round 2
// 94.876 us; speedup vs baseline: 1.4561x; 1.4561x over previous
//
#include <hip/hip_runtime.h>
#include <math.h>

#define NP 16384   // spatial positions = 32*32*16
#define HDIM 32
#define WDIM 32
#define ZDIM 16

// ---------------------------------------------------------------------------
// Tiled f32 GEMM: C[o][p] = sum_c A[o][c] * B[c][p] + bias[o]
// A: M x 128 row-major, B: 128 x NP, C: M x NP.
// BM=64, BN=128, BK=64 (2 passes). Grid: (NP/128, M/64), 256 threads.
// Micro-tile 4x8 per thread: 32 FMA per 3 ds_read_b128.
// ---------------------------------------------------------------------------
__global__ __launch_bounds__(256) void gemm_f32_v2(
    const float* __restrict__ A, const float* __restrict__ B,
    const float* __restrict__ bias, float* __restrict__ C)
{
    __shared__ __align__(16) float Ws[64][68];   // [c][o_local], stride 68 (16B-mult)
    __shared__ __align__(16) float Xs[64][128];  // [c][p_local]

    const int o0 = blockIdx.y * 64;
    const int p0 = blockIdx.x * 128;
    const int tid = threadIdx.x;
    const int tx = tid & 15;   // p group (8 floats)
    const int ty = tid >> 4;   // o group (4 floats)

    float acc[4][8];
    #pragma unroll
    for (int i = 0; i < 4; ++i)
        #pragma unroll
        for (int j = 0; j < 8; ++j) acc[i][j] = 0.f;

    for (int kt = 0; kt < 2; ++kt) {
        const int c0 = kt * 64;
        // A tile transposed: Ws[c][i] = A[(o0+i)*128 + c0+c]
        #pragma unroll
        for (int e = tid; e < 64 * 64; e += 256) {
            const int i = e >> 6;
            const int c = e & 63;
            Ws[c][i] = A[(o0 + i) * 128 + c0 + c];
        }
        // B tile: Xs[c][j] = B[(c0+c)*NP + p0 + j] (float4)
        #pragma unroll
        for (int e = tid; e < 64 * 32; e += 256) {
            const int c = e >> 5;
            const int j = (e & 31) * 4;
            *(float4*)&Xs[c][j] = *(const float4*)&B[(c0 + c) * NP + p0 + j];
        }
        __syncthreads();

        #pragma unroll 4
        for (int kk = 0; kk < 64; ++kk) {
            const float4 af = *(const float4*)&Ws[kk][ty * 4];
            const float4 b0 = *(const float4*)&Xs[kk][tx * 8];
            const float4 b1 = *(const float4*)&Xs[kk][tx * 8 + 4];
            const float av[4] = {af.x, af.y, af.z, af.w};
            const float bv[8] = {b0.x, b0.y, b0.z, b0.w, b1.x, b1.y, b1.z, b1.w};
            #pragma unroll
            for (int i = 0; i < 4; ++i)
                #pragma unroll
                for (int j = 0; j < 8; ++j)
                    acc[i][j] = fmaf(av[i], bv[j], acc[i][j]);
        }
        __syncthreads();
    }

    #pragma unroll
    for (int i = 0; i < 4; ++i) {
        const int o = o0 + ty * 4 + i;
        const float bo = bias[o];
        float4 r0, r1;
        r0.x = acc[i][0] + bo; r0.y = acc[i][1] + bo;
        r0.z = acc[i][2] + bo; r0.w = acc[i][3] + bo;
        r1.x = acc[i][4] + bo; r1.y = acc[i][5] + bo;
        r1.z = acc[i][6] + bo; r1.w = acc[i][7] + bo;
        *(float4*)&C[o * NP + p0 + tx * 8]     = r0;
        *(float4*)&C[o * NP + p0 + tx * 8 + 4] = r1;
    }
}

// ---------------------------------------------------------------------------
// 3D neighborhood attention, k=3x3x3, NATTEN clamped windows.
// qkv layout: [384][NP]; q rows 0..127, k 128..255, v 256..383.
// 4 lanes cooperate per (head, position): lane = z + 16*chunk; each chunk
// owns 8 of the 32 head-channels. Wave = one (h,w) z-column (uniform clamps).
// Grid: (1024/4, heads) = (256, 4), 256 threads (4 waves).
// ---------------------------------------------------------------------------
__global__ __launch_bounds__(256) void natten3d_v2(
    const float* __restrict__ qkv, const float* __restrict__ rpb,
    float* __restrict__ attnout)
{
    const int tid  = threadIdx.x;
    const int head = blockIdx.y;
    const int lane = tid & 63;
    const int wave = tid >> 6;
    const int z     = lane & 15;
    const int chunk = lane >> 4;                 // 0..3, 8 channels each
    const int col   = blockIdx.x * 4 + wave;     // (h,w) column index, 0..1023
    const int h = col >> 5;
    const int w = col & 31;
    const int p = col * 16 + z;

    __shared__ float bias_s[125];
    if (tid < 125) bias_s[tid] = rpb[head * 125 + tid];
    __syncthreads();

    const float scale = 0.17677669529663687f;  // 32^-0.5
    const float* __restrict__ qb = qkv + (head * 32 + chunk * 8) * NP;
    const float* __restrict__ kb = qkv + (128 + head * 32 + chunk * 8) * NP;
    const float* __restrict__ vb = qkv + (256 + head * 32 + chunk * 8) * NP;

    float q[8];
    #pragma unroll
    for (int d = 0; d < 8; ++d) q[d] = qb[d * NP + p] * scale;

    int hs = h - 1; hs = hs < 0 ? 0 : (hs > HDIM - 3 ? HDIM - 3 : hs);
    int ws_ = w - 1; ws_ = ws_ < 0 ? 0 : (ws_ > WDIM - 3 ? WDIM - 3 : ws_);
    int zs = z - 1; zs = zs < 0 ? 0 : (zs > ZDIM - 3 ? ZDIM - 3 : zs);
    const int rh0 = hs - h + 2;
    const int rw0 = ws_ - w + 2;
    const int rz0 = zs - z + 2;

    float s[27];
    float smax = -1e30f;
    #pragma unroll
    for (int dh = 0; dh < 3; ++dh) {
        #pragma unroll
        for (int dw = 0; dw < 3; ++dw) {
            #pragma unroll
            for (int dz = 0; dz < 3; ++dz) {
                const int m = (dh * 3 + dw) * 3 + dz;
                const int pn = (hs + dh) * 512 + (ws_ + dw) * 16 + (zs + dz);
                float acc = 0.f;
                #pragma unroll
                for (int d = 0; d < 8; ++d)
                    acc = fmaf(q[d], kb[d * NP + pn], acc);
                // combine the 4 channel-chunks (lanes z, z+16, z+32, z+48)
                acc += __shfl_xor(acc, 16, 64);
                acc += __shfl_xor(acc, 32, 64);
                acc += bias_s[((rh0 + dh) * 5 + (rw0 + dw)) * 5 + (rz0 + dz)];
                s[m] = acc;
                smax = fmaxf(smax, acc);
            }
        }
    }

    float ssum = 0.f;
    #pragma unroll
    for (int m = 0; m < 27; ++m) {
        s[m] = __expf(s[m] - smax);
        ssum += s[m];
    }
    const float inv = 1.f / ssum;

    float o[8];
    #pragma unroll
    for (int d = 0; d < 8; ++d) o[d] = 0.f;

    #pragma unroll
    for (int dh = 0; dh < 3; ++dh) {
        #pragma unroll
        for (int dw = 0; dw < 3; ++dw) {
            #pragma unroll
            for (int dz = 0; dz < 3; ++dz) {
                const int m = (dh * 3 + dw) * 3 + dz;
                const int pn = (hs + dh) * 512 + (ws_ + dw) * 16 + (zs + dz);
                const float pm = s[m];
                #pragma unroll
                for (int d = 0; d < 8; ++d)
                    o[d] = fmaf(pm, vb[d * NP + pn], o[d]);
            }
        }
    }

    #pragma unroll
    for (int d = 0; d < 8; ++d)
        attnout[(head * 32 + chunk * 8 + d) * NP + p] = o[d] * inv;
}

// ---------------------------------------------------------------------------
extern "C" void kernel_launch(void* const* d_in, const int* in_sizes, int n_in,
                              void* d_out, int out_size, void* d_ws, size_t ws_size,
                              hipStream_t stream)
{
    const float* x    = (const float*)d_in[0];  // (1,128,32,32,16)
    const float* Wqkv = (const float*)d_in[1];  // (384,128)
    const float* bqkv = (const float*)d_in[2];  // (384,)
    const float* rpb  = (const float*)d_in[3];  // (4,5,5,5)
    const float* Wp   = (const float*)d_in[4];  // (128,128)
    const float* bp   = (const float*)d_in[5];  // (128,)
    float* out = (float*)d_out;                 // (1,128,32,32,16)

    float* qkv     = (float*)d_ws;              // 384*NP f32 = 24 MB
    float* attnout = qkv + 384 * NP;            // 128*NP f32 =  8 MB

    // 1) QKV projection
    gemm_f32_v2<<<dim3(NP / 128, 6), dim3(256), 0, stream>>>(Wqkv, x, bqkv, qkv);

    // 2) neighborhood attention
    natten3d_v2<<<dim3(256, 4), dim3(256), 0, stream>>>(qkv, rpb, attnout);

    // 3) output projection
    gemm_f32_v2<<<dim3(NP / 128, 2), dim3(256), 0, stream>>>(Wp, attnout, bp, out);
}